// Round 2
// baseline (1099.932 us; speedup 1.0000x reference)
//
#include <hip/hip_runtime.h>

// ---------------------------------------------------------------------------
// SelfAttention forward (N=2, L=2048, E=1024, H=16, D=64), f32 in/out.
// Outputs concatenated: out | q | k | v | energy | attention
//
// Structure (6 launches, no converts):
//  1-3) projections q/k/v: f32 x,W inline-cvt -> bf16 MFMA -> f32 q/k/v.
//       k also dual-writes kb bf16 into dead `out` region (bytes 8..16MB).
//  4)   transpose vf f32 -> vt bf16 [nh][d][l] into `out` region (bytes 0..8MB).
//  5)   fused attention: per (head, 64 q-rows) block, stream K in 128-col
//       chunks: QK^T MFMA -> write energy -> p=exp(s/8) (NO max pass: |S|<~16
//       so exp(S/8)<=e^2, f32-safe) -> row-sums l online -> P bf16 -> LDS
//       (XOR-swizzle, per-wave region, zero barriers) -> PV accumulate.
//       Epilogue: head = O/l (bf16, d_ws). Pass 2: recompute QK^T (K in L2,
//       cheaper than re-reading 536MB energy) -> attention = exp/l.
//  6)   out-projection: head bf16 @ Wo^T (f32 inline) + bo -> out.
// ---------------------------------------------------------------------------

typedef __attribute__((ext_vector_type(8))) short     s16x8;   // 8 bf16
typedef __attribute__((ext_vector_type(4))) float     f32x4;
typedef __attribute__((ext_vector_type(8))) unsigned short u16x8;

#define DEVINL __device__ __forceinline__

DEVINL unsigned short f2b(float f) {           // f32 -> bf16 (RNE)
  unsigned int u = __builtin_bit_cast(unsigned int, f);
  u = (u + 0x7FFFu + ((u >> 16) & 1u)) >> 16;
  return (unsigned short)u;
}

DEVINL s16x8 pack8(float4 a, float4 b) {
  s16x8 r;
  r[0] = (short)f2b(a.x); r[1] = (short)f2b(a.y);
  r[2] = (short)f2b(a.z); r[3] = (short)f2b(a.w);
  r[4] = (short)f2b(b.x); r[5] = (short)f2b(b.y);
  r[6] = (short)f2b(b.z); r[7] = (short)f2b(b.w);
  return r;
}

DEVINL f32x4 mfma16(s16x8 a, s16x8 b, f32x4 c) {
  return __builtin_amdgcn_mfma_f32_16x16x32_bf16(a, b, c, 0, 0, 0);
}

// ---------------------------------------------------------------------------
// Projection / output GEMM:  C[m][n] = sum_k A[m][k]*B[n][k] + bias[n]
// M=4096, N=1024, K=1024, all leading dims 1024.
// AF32: A is f32 (inline cvt); else A is bf16. B always f32 (weights).
// WB16: additionally write bf16 copy of C to Cb (same layout).
// Block: 4 waves, tile 64(M) x 128(N); wave 32x64; grid (8, 64).
// ---------------------------------------------------------------------------
template<bool AF32, bool WB16>
__global__ __launch_bounds__(256) void gemm_proj(
    const void* __restrict__ Av, const float* __restrict__ B,
    const float* __restrict__ bias, float* __restrict__ Cf,
    unsigned short* __restrict__ Cb) {
  int t = threadIdx.x, lane = t & 63, w = t >> 6;
  int m0 = blockIdx.y * 64 + (w >> 1) * 32;
  int n0 = blockIdx.x * 128 + (w & 1) * 64;
  int lr = lane & 15, kg = (lane >> 4) * 8;

  f32x4 acc[2][4] = {};
  const float* Af = (const float*)Av;
  const unsigned short* Ab = (const unsigned short*)Av;

  for (int k0 = 0; k0 < 1024; k0 += 32) {
    s16x8 a0, a1;
    if (AF32) {
      const float* p0 = Af + (size_t)(m0 + lr) * 1024 + k0 + kg;
      const float* p1 = p0 + 16 * 1024;
      a0 = pack8(*(const float4*)p0, *(const float4*)(p0 + 4));
      a1 = pack8(*(const float4*)p1, *(const float4*)(p1 + 4));
    } else {
      const unsigned short* p0 = Ab + (size_t)(m0 + lr) * 1024 + k0 + kg;
      a0 = *(const s16x8*)p0;
      a1 = *(const s16x8*)(p0 + 16 * 1024);
    }
    #pragma unroll
    for (int j = 0; j < 4; j++) {
      const float* bp = B + (size_t)(n0 + j * 16 + lr) * 1024 + k0 + kg;
      s16x8 bf = pack8(*(const float4*)bp, *(const float4*)(bp + 4));
      acc[0][j] = mfma16(a0, bf, acc[0][j]);
      acc[1][j] = mfma16(a1, bf, acc[1][j]);
    }
  }

  int rb = (lane >> 4) * 4;
  #pragma unroll
  for (int i = 0; i < 2; i++) {
    #pragma unroll
    for (int j = 0; j < 4; j++) {
      int col = n0 + j * 16 + lr;
      float bv = bias[col];
      #pragma unroll
      for (int r = 0; r < 4; r++) {
        int row = m0 + i * 16 + rb + r;
        float v = acc[i][j][r] + bv;
        size_t idx = (size_t)row * 1024 + col;
        Cf[idx] = v;
        if (WB16) Cb[idx] = f2b(v);
      }
    }
  }
}

// ---------------------------------------------------------------------------
// v (f32, [n][l][h*64+d]) -> vt (bf16, [n*16+h][d][l])  via LDS tile
// grid: (L/64, N*H) blocks of 256
// ---------------------------------------------------------------------------
__global__ __launch_bounds__(256) void transpose_v_k(
    const float* __restrict__ vf, unsigned short* __restrict__ vt) {
  __shared__ unsigned short tile[64][72];
  int nh = blockIdx.y, n = nh >> 4, h = nh & 15;
  int l0 = blockIdx.x * 64;
  int t = threadIdx.x;
  int lr = t >> 2;
  int dc = (t & 3) * 16;
  const float* src = vf + ((size_t)(n * 2048 + l0 + lr)) * 1024 + h * 64 + dc;
  float4 a = *(const float4*)(src);
  float4 b = *(const float4*)(src + 4);
  float4 c = *(const float4*)(src + 8);
  float4 e = *(const float4*)(src + 12);
  float vals[16] = {a.x, a.y, a.z, a.w, b.x, b.y, b.z, b.w,
                    c.x, c.y, c.z, c.w, e.x, e.y, e.z, e.w};
  #pragma unroll
  for (int j = 0; j < 16; j++) tile[dc + j][lr] = f2b(vals[j]);
  __syncthreads();
  int dr = t >> 2;
  int lc = (t & 3) * 16;
  unsigned short* dst = vt + ((size_t)nh * 64 + dr) * 2048 + l0 + lc;
  *(u16x8*)(dst)     = *(const u16x8*)&tile[dr][lc];
  *(u16x8*)(dst + 8) = *(const u16x8*)&tile[dr][lc + 8];
}

// ---------------------------------------------------------------------------
// Fused attention. Grid (32 qtiles, 32 nh), 256 threads (4 waves).
// Wave w owns q-rows q0+w*16 .. +15 for the whole kernel (no barriers).
// ---------------------------------------------------------------------------
DEVINL void qk_chunk(const unsigned short* __restrict__ Kb, int c0, int lr,
                     int kg, s16x8 aq0, s16x8 aq1, f32x4* s) {
  #pragma unroll
  for (int j = 0; j < 8; j++) {
    const unsigned short* kcol = Kb + (size_t)(c0 + j * 16 + lr) * 1024 + kg;
    s16x8 b0 = *(const s16x8*)kcol;
    s16x8 b1 = *(const s16x8*)(kcol + 32);
    f32x4 z = {};
    z = mfma16(aq0, b0, z);
    s[j] = mfma16(aq1, b1, z);
  }
}

__global__ __launch_bounds__(256) void fused_attn_k(
    const float* __restrict__ qf, const unsigned short* __restrict__ kb,
    const unsigned short* __restrict__ vt, float* __restrict__ energy,
    float* __restrict__ attn, unsigned short* __restrict__ head) {
  __shared__ unsigned short plds[4][2048];   // 4KB per wave, XOR-swizzled
  int nh = blockIdx.y, n = nh >> 4, h = nh & 15;
  int q0 = blockIdx.x * 64;
  int t = threadIdx.x, w = t >> 6, lane = t & 63;
  int lr = lane & 15, g = lane >> 4, kg = g * 8, rb = g * 4;

  // Q fragments, held in registers the whole kernel
  const float* qrow = qf + ((size_t)(n * 2048 + q0 + w * 16 + lr)) * 1024 + h * 64;
  s16x8 aq0 = pack8(*(const float4*)(qrow + kg), *(const float4*)(qrow + kg + 4));
  s16x8 aq1 = pack8(*(const float4*)(qrow + 32 + kg),
                    *(const float4*)(qrow + 32 + kg + 4));

  const unsigned short* Kb = kb + (size_t)n * (2048 * 1024) + h * 64;
  const unsigned short* Vb = vt + (size_t)nh * (64 * 2048);
  float* erow = energy + (size_t)nh * (2048ull * 2048ull) +
                (size_t)(q0 + w * 16) * 2048;
  float* arow = attn + (size_t)nh * (2048ull * 2048ull) +
                (size_t)(q0 + w * 16) * 2048;

  float lsum[4] = {0.f, 0.f, 0.f, 0.f};
  f32x4 acc_o[4] = {};
  char* pw = (char*)&plds[w][0];

  // ---- pass 1: energy write + online sums + unnormalized PV ----
  for (int c0 = 0; c0 < 2048; c0 += 128) {
    f32x4 s[8];
    qk_chunk(Kb, c0, lr, kg, aq0, aq1, s);
    #pragma unroll
    for (int j = 0; j < 8; j++) {
      #pragma unroll
      for (int r = 0; r < 4; r++) {
        float v = s[j][r];
        erow[(size_t)(rb + r) * 2048 + c0 + j * 16 + lr] = v;
        float p = __expf(v * 0.125f);
        lsum[r] += p;
        int row = rb + r;
        int off = (row * 256 + (j * 16 + lr) * 2) ^ ((row & 7) << 4);
        *(unsigned short*)(pw + off) = f2b(p);
      }
    }
    #pragma unroll
    for (int m = 0; m < 4; m++) {
      int koff = m * 32 + kg;
      s16x8 pa = *(const s16x8*)(pw + ((lr * 256 + koff * 2) ^ ((lr & 7) << 4)));
      #pragma unroll
      for (int nf = 0; nf < 4; nf++) {
        s16x8 bv = *(const s16x8*)(Vb + (size_t)(nf * 16 + lr) * 2048 + c0 + koff);
        acc_o[nf] = mfma16(pa, bv, acc_o[nf]);
      }
    }
  }

  // row sums -> reciprocals (reduce over the 16 lanes of each row group)
  float inv[4];
  #pragma unroll
  for (int r = 0; r < 4; r++) {
    float v = lsum[r];
    v += __shfl_xor(v, 1); v += __shfl_xor(v, 2);
    v += __shfl_xor(v, 4); v += __shfl_xor(v, 8);
    inv[r] = 1.0f / v;
  }

  // head = O / l  (bf16)
  unsigned short* hrow = head + ((size_t)(n * 2048 + q0 + w * 16)) * 1024 + h * 64;
  #pragma unroll
  for (int nf = 0; nf < 4; nf++) {
    #pragma unroll
    for (int r = 0; r < 4; r++) {
      hrow[(size_t)(rb + r) * 1024 + nf * 16 + lr] = f2b(acc_o[nf][r] * inv[r]);
    }
  }

  // ---- pass 2: attention write (recompute S from L2-resident K) ----
  for (int c0 = 0; c0 < 2048; c0 += 128) {
    f32x4 s[8];
    qk_chunk(Kb, c0, lr, kg, aq0, aq1, s);
    #pragma unroll
    for (int j = 0; j < 8; j++) {
      #pragma unroll
      for (int r = 0; r < 4; r++) {
        arow[(size_t)(rb + r) * 2048 + c0 + j * 16 + lr] =
            __expf(s[j][r] * 0.125f) * inv[r];
      }
    }
  }
}

// ---------------------------------------------------------------------------
extern "C" void kernel_launch(void* const* d_in, const int* in_sizes, int n_in,
                              void* d_out, int out_size, void* d_ws, size_t ws_size,
                              hipStream_t stream) {
  const float* Vin = (const float*)d_in[0];
  const float* Kin = (const float*)d_in[1];
  const float* Qin = (const float*)d_in[2];
  const float* Wq  = (const float*)d_in[3];
  const float* bq  = (const float*)d_in[4];
  const float* Wk  = (const float*)d_in[5];
  const float* bk  = (const float*)d_in[6];
  const float* Wv  = (const float*)d_in[7];
  const float* bv  = (const float*)d_in[8];
  const float* Wo  = (const float*)d_in[9];
  const float* bo  = (const float*)d_in[10];

  float* out    = (float*)d_out;
  float* qf     = out + 4194304;          // (2,2048,16,64) == (4096,1024) f32
  float* kf     = out + 8388608;
  float* vf     = out + 12582912;
  float* energy = out + 16777216;         // (2,16,2048,2048) f32
  float* attn   = out + 150994944;

  // dead `out` region (16 MB) hosts vt bf16 (8 MB) + kb bf16 (8 MB)
  unsigned short* vt = (unsigned short*)out;            // [nh][64][2048]
  unsigned short* kb = (unsigned short*)out + 4194304;  // [n][l][e] bf16
  // d_ws: head bf16 (8 MB)
  unsigned short* head = (unsigned short*)d_ws;

  // 1-3) projections (f32 inputs/weights, inline cvt)
  gemm_proj<true, false><<<dim3(8, 64), 256, 0, stream>>>(Qin, Wq, bq, qf, nullptr);
  gemm_proj<true, true ><<<dim3(8, 64), 256, 0, stream>>>(Kin, Wk, bk, kf, kb);
  gemm_proj<true, false><<<dim3(8, 64), 256, 0, stream>>>(Vin, Wv, bv, vf, nullptr);

  // 4) v^T bf16
  transpose_v_k<<<dim3(32, 32), 256, 0, stream>>>(vf, vt);

  // 5) fused energy + softmax + PV
  fused_attn_k<<<dim3(32, 32), 256, 0, stream>>>(qf, kb, vt, energy, attn, head);

  // 6) out = head @ Wo^T + bo
  gemm_proj<false, false><<<dim3(8, 64), 256, 0, stream>>>(head, Wo, bo, out, nullptr);
}

// Round 3
// 741.722 us; speedup vs baseline: 1.4829x; 1.4829x over previous
//
#include <hip/hip_runtime.h>

// ---------------------------------------------------------------------------
// SelfAttention forward (N=2, L=2048, E=1024, H=16, D=64), f32 in/out.
// Outputs concatenated: out | q | k | v | energy | attention
//
// Round-3 structure:
//  0) 4 tiny converts: Wq/Wk/Wv -> bf16 (dead energy region), Wo -> d_ws.
//  1-3) projections q/k/v: A f32 inline-cvt, B bf16 -> f32 q/k/v.
//       k dual-writes kb bf16 into dead `out` region (bytes 8..16MB).
//  4) transpose vf f32 -> vt bf16 [nh][d][l] into `out` region (bytes 0..8MB).
//  5) fused attention, LDS-staged coalesced stores:
//     per chunk (128 cols): QK^T MFMA -> C-layout s into LDS f32 tile
//     [64][132] -> barrier -> (a) block-cooperative float4 energy store
//     (512B contiguous per row), (b) own-slab A-layout re-read + exp ->
//     P bf16 frags -> PV MFMA + online row-sums -> barrier.
//     Epilogue: head = O/l (bf16, d_ws). Pass 2: recompute QK^T (K L2-hot),
//     attention = exp*inv staged the same way.
//     No max subtraction: |S| <~ 16 so exp(S/8) <= e^2, f32-safe.
//  6) out-projection: head bf16 @ Wo^T + bo -> out.
// ---------------------------------------------------------------------------

typedef __attribute__((ext_vector_type(8))) short     s16x8;   // 8 bf16
typedef __attribute__((ext_vector_type(4))) float     f32x4;
typedef __attribute__((ext_vector_type(8))) unsigned short u16x8;
typedef __attribute__((ext_vector_type(4))) unsigned short u16x4;

#define DEVINL __device__ __forceinline__

DEVINL unsigned short f2b(float f) {           // f32 -> bf16 (RNE)
  unsigned int u = __builtin_bit_cast(unsigned int, f);
  u = (u + 0x7FFFu + ((u >> 16) & 1u)) >> 16;
  return (unsigned short)u;
}

DEVINL s16x8 pack8(float4 a, float4 b) {
  s16x8 r;
  r[0] = (short)f2b(a.x); r[1] = (short)f2b(a.y);
  r[2] = (short)f2b(a.z); r[3] = (short)f2b(a.w);
  r[4] = (short)f2b(b.x); r[5] = (short)f2b(b.y);
  r[6] = (short)f2b(b.z); r[7] = (short)f2b(b.w);
  return r;
}

DEVINL f32x4 mfma16(s16x8 a, s16x8 b, f32x4 c) {
  return __builtin_amdgcn_mfma_f32_16x16x32_bf16(a, b, c, 0, 0, 0);
}

// ---------------------------------------------------------------------------
__global__ __launch_bounds__(256) void f32_to_bf16_k(
    const float* __restrict__ s, unsigned short* __restrict__ d, int n) {
  int i = (blockIdx.x * 256 + threadIdx.x) * 4;
  if (i < n) {
    float4 v = *(const float4*)(s + i);
    u16x4 o;
    o[0] = f2b(v.x); o[1] = f2b(v.y); o[2] = f2b(v.z); o[3] = f2b(v.w);
    *(u16x4*)(d + i) = o;
  }
}

// ---------------------------------------------------------------------------
// Projection / output GEMM:  C[m][n] = sum_k A[m][k]*B[n][k] + bias[n]
// M=4096, N=1024, K=1024. B is bf16. AF32: A f32 inline-cvt, else bf16.
// Block: 4 waves, tile 64(M) x 128(N); wave 32x64; grid (8, 64).
// ---------------------------------------------------------------------------
template<bool AF32, bool WB16>
__global__ __launch_bounds__(256) void gemm_proj(
    const void* __restrict__ Av, const unsigned short* __restrict__ Bb,
    const float* __restrict__ bias, float* __restrict__ Cf,
    unsigned short* __restrict__ Cb) {
  int t = threadIdx.x, lane = t & 63, w = t >> 6;
  int m0 = blockIdx.y * 64 + (w >> 1) * 32;
  int n0 = blockIdx.x * 128 + (w & 1) * 64;
  int lr = lane & 15, kg = (lane >> 4) * 8;

  f32x4 acc[2][4] = {};
  const float* Af = (const float*)Av;
  const unsigned short* Ab = (const unsigned short*)Av;

  for (int k0 = 0; k0 < 1024; k0 += 32) {
    s16x8 a0, a1;
    if (AF32) {
      const float* p0 = Af + (size_t)(m0 + lr) * 1024 + k0 + kg;
      const float* p1 = p0 + 16 * 1024;
      a0 = pack8(*(const float4*)p0, *(const float4*)(p0 + 4));
      a1 = pack8(*(const float4*)p1, *(const float4*)(p1 + 4));
    } else {
      const unsigned short* p0 = Ab + (size_t)(m0 + lr) * 1024 + k0 + kg;
      a0 = *(const s16x8*)p0;
      a1 = *(const s16x8*)(p0 + 16 * 1024);
    }
    #pragma unroll
    for (int j = 0; j < 4; j++) {
      s16x8 bf = *(const s16x8*)(Bb + (size_t)(n0 + j * 16 + lr) * 1024 + k0 + kg);
      acc[0][j] = mfma16(a0, bf, acc[0][j]);
      acc[1][j] = mfma16(a1, bf, acc[1][j]);
    }
  }

  int rb = (lane >> 4) * 4;
  #pragma unroll
  for (int i = 0; i < 2; i++) {
    #pragma unroll
    for (int j = 0; j < 4; j++) {
      int col = n0 + j * 16 + lr;
      float bv = bias[col];
      #pragma unroll
      for (int r = 0; r < 4; r++) {
        int row = m0 + i * 16 + rb + r;
        float v = acc[i][j][r] + bv;
        size_t idx = (size_t)row * 1024 + col;
        Cf[idx] = v;
        if (WB16) Cb[idx] = f2b(v);
      }
    }
  }
}

// ---------------------------------------------------------------------------
// v (f32, [n][l][h*64+d]) -> vt (bf16, [n*16+h][d][l])
// ---------------------------------------------------------------------------
__global__ __launch_bounds__(256) void transpose_v_k(
    const float* __restrict__ vf, unsigned short* __restrict__ vt) {
  __shared__ unsigned short tile[64][72];
  int nh = blockIdx.y, n = nh >> 4, h = nh & 15;
  int l0 = blockIdx.x * 64;
  int t = threadIdx.x;
  int lr = t >> 2;
  int dc = (t & 3) * 16;
  const float* src = vf + ((size_t)(n * 2048 + l0 + lr)) * 1024 + h * 64 + dc;
  float4 a = *(const float4*)(src);
  float4 b = *(const float4*)(src + 4);
  float4 c = *(const float4*)(src + 8);
  float4 e = *(const float4*)(src + 12);
  float vals[16] = {a.x, a.y, a.z, a.w, b.x, b.y, b.z, b.w,
                    c.x, c.y, c.z, c.w, e.x, e.y, e.z, e.w};
  #pragma unroll
  for (int j = 0; j < 16; j++) tile[dc + j][lr] = f2b(vals[j]);
  __syncthreads();
  int dr = t >> 2;
  int lc = (t & 3) * 16;
  unsigned short* dst = vt + ((size_t)nh * 64 + dr) * 2048 + l0 + lc;
  *(u16x8*)(dst)     = *(const u16x8*)&tile[dr][lc];
  *(u16x8*)(dst + 8) = *(const u16x8*)&tile[dr][lc + 8];
}

// ---------------------------------------------------------------------------
// Fused attention. Grid (32,32) -> 1024 blocks, XCD-swizzled.
// 4 waves; wave w owns q-rows w*16..w*16+15 of its 64-row block.
// LDS: one f32 tile [64][132] (33KB) staged per 128-col chunk.
// ---------------------------------------------------------------------------
DEVINL void qk_chunk(const unsigned short* __restrict__ Kb, int c0, int lr,
                     int kg, s16x8 aq0, s16x8 aq1, f32x4* s) {
  #pragma unroll
  for (int j = 0; j < 8; j++) {
    const unsigned short* kcol = Kb + (size_t)(c0 + j * 16 + lr) * 1024 + kg;
    s16x8 b0 = *(const s16x8*)kcol;
    s16x8 b1 = *(const s16x8*)(kcol + 32);
    f32x4 z = {};
    z = mfma16(aq0, b0, z);
    s[j] = mfma16(aq1, b1, z);
  }
}

__global__ __launch_bounds__(256) void fused_attn_k(
    const float* __restrict__ qf, const unsigned short* __restrict__ kb,
    const unsigned short* __restrict__ vt, float* __restrict__ energy,
    float* __restrict__ attn, unsigned short* __restrict__ head) {
  __shared__ float tile[64][132];            // 33792 B, +4 pad
  int bid = blockIdx.y * 32 + blockIdx.x;
  int cid = (bid & 7) * 128 + (bid >> 3);    // XCD-contiguous remap (1024%8==0)
  int nh = cid >> 5, qt = cid & 31;
  int n = nh >> 4, h = nh & 15;
  int q0 = qt * 64;
  int t = threadIdx.x, w = t >> 6, lane = t & 63;
  int lr = lane & 15, g = lane >> 4, kg = g * 8, rb = g * 4;
  int wrow = w * 16;

  // Q fragments (held all kernel)
  const float* qrow = qf + ((size_t)(n * 2048 + q0 + wrow + lr)) * 1024 + h * 64;
  s16x8 aq0 = pack8(*(const float4*)(qrow + kg), *(const float4*)(qrow + kg + 4));
  s16x8 aq1 = pack8(*(const float4*)(qrow + 32 + kg),
                    *(const float4*)(qrow + 32 + kg + 4));

  const unsigned short* Kb = kb + (size_t)n * (2048 * 1024) + h * 64;
  const unsigned short* Vb = vt + (size_t)nh * (64 * 2048);
  float* eblk = energy + (size_t)nh * (2048ull * 2048ull) + (size_t)q0 * 2048;
  float* ablk = attn + (size_t)nh * (2048ull * 2048ull) + (size_t)q0 * 2048;

  float lsum = 0.f;          // A-layout partial row sum: row = wrow+lr
  f32x4 acc_o[4] = {};

  int crow = t >> 5;         // coop-store: 8 threads... 32 thr/row
  int ccol = (t & 31) * 4;

  // ---- pass 1: energy + PV ----
  for (int c0 = 0; c0 < 2048; c0 += 128) {
    f32x4 s[8];
    qk_chunk(Kb, c0, lr, kg, aq0, aq1, s);
    #pragma unroll
    for (int j = 0; j < 8; j++)
      #pragma unroll
      for (int r = 0; r < 4; r++)
        tile[wrow + rb + r][j * 16 + lr] = s[j][r];
    __syncthreads();

    // (a) cooperative coalesced energy store: 512B contiguous per row
    float* ebase = eblk + c0;
    #pragma unroll
    for (int i = 0; i < 8; i++) {
      int row = crow + i * 8;
      *(float4*)(ebase + (size_t)row * 2048 + ccol) =
          *(const float4*)&tile[row][ccol];
    }

    // (b) own-slab exp in A-fragment layout -> PV
    #pragma unroll
    for (int m = 0; m < 4; m++) {
      const float* pr = &tile[wrow + lr][m * 32 + kg];
      float4 x0 = *(const float4*)pr;
      float4 x1 = *(const float4*)(pr + 4);
      float e0 = __expf(x0.x * 0.125f), e1 = __expf(x0.y * 0.125f);
      float e2 = __expf(x0.z * 0.125f), e3 = __expf(x0.w * 0.125f);
      float e4 = __expf(x1.x * 0.125f), e5 = __expf(x1.y * 0.125f);
      float e6 = __expf(x1.z * 0.125f), e7 = __expf(x1.w * 0.125f);
      lsum += (e0 + e1 + e2 + e3) + (e4 + e5 + e6 + e7);
      s16x8 pa;
      pa[0] = (short)f2b(e0); pa[1] = (short)f2b(e1);
      pa[2] = (short)f2b(e2); pa[3] = (short)f2b(e3);
      pa[4] = (short)f2b(e4); pa[5] = (short)f2b(e5);
      pa[6] = (short)f2b(e6); pa[7] = (short)f2b(e7);
      #pragma unroll
      for (int nf = 0; nf < 4; nf++) {
        s16x8 bv = *(const s16x8*)(Vb + (size_t)(nf * 16 + lr) * 2048 +
                                   c0 + m * 32 + kg);
        acc_o[nf] = mfma16(pa, bv, acc_o[nf]);
      }
    }
    __syncthreads();
  }

  // row sums: reduce A-layout partials over lane groups (same lr, 4 g's)
  lsum += __shfl_xor(lsum, 16);
  lsum += __shfl_xor(lsum, 32);
  float inv = 1.0f / lsum;               // valid for row = wrow + lr
  float invr[4];
  #pragma unroll
  for (int r = 0; r < 4; r++) invr[r] = __shfl(inv, rb + r);  // lanes 0..15

  // head = O / l  (bf16)
  unsigned short* hrow = head + ((size_t)(n * 2048 + q0 + wrow)) * 1024 + h * 64;
  #pragma unroll
  for (int nf = 0; nf < 4; nf++)
    #pragma unroll
    for (int r = 0; r < 4; r++)
      hrow[(size_t)(rb + r) * 1024 + nf * 16 + lr] = f2b(acc_o[nf][r] * invr[r]);

  // ---- pass 2: attention = exp(s/8)*inv, staged + coalesced ----
  for (int c0 = 0; c0 < 2048; c0 += 128) {
    f32x4 s[8];
    qk_chunk(Kb, c0, lr, kg, aq0, aq1, s);
    #pragma unroll
    for (int j = 0; j < 8; j++)
      #pragma unroll
      for (int r = 0; r < 4; r++)
        tile[wrow + rb + r][j * 16 + lr] = __expf(s[j][r] * 0.125f) * invr[r];
    __syncthreads();
    float* abase = ablk + c0;
    #pragma unroll
    for (int i = 0; i < 8; i++) {
      int row = crow + i * 8;
      *(float4*)(abase + (size_t)row * 2048 + ccol) =
          *(const float4*)&tile[row][ccol];
    }
    __syncthreads();
  }
}

// ---------------------------------------------------------------------------
extern "C" void kernel_launch(void* const* d_in, const int* in_sizes, int n_in,
                              void* d_out, int out_size, void* d_ws, size_t ws_size,
                              hipStream_t stream) {
  const float* Vin = (const float*)d_in[0];
  const float* Kin = (const float*)d_in[1];
  const float* Qin = (const float*)d_in[2];
  const float* Wq  = (const float*)d_in[3];
  const float* bq  = (const float*)d_in[4];
  const float* Wk  = (const float*)d_in[5];
  const float* bk  = (const float*)d_in[6];
  const float* Wv  = (const float*)d_in[7];
  const float* bv  = (const float*)d_in[8];
  const float* Wo  = (const float*)d_in[9];
  const float* bo  = (const float*)d_in[10];

  float* out    = (float*)d_out;
  float* qf     = out + 4194304;          // (4096,1024) f32
  float* kf     = out + 8388608;
  float* vf     = out + 12582912;
  float* energy = out + 16777216;         // (2,16,2048,2048) f32
  float* attn   = out + 150994944;

  // dead `out` region (16 MB): vt bf16 (8 MB) + kb bf16 (8 MB)
  unsigned short* vt = (unsigned short*)out;            // [nh][64][2048]
  unsigned short* kb = (unsigned short*)out + 4194304;  // [n*l][e] bf16
  // dead energy region hosts bf16 weights during projections
  unsigned short* wqb = (unsigned short*)energy;
  unsigned short* wkb = wqb + 1048576;
  unsigned short* wvb = wkb + 1048576;
  // d_ws: head bf16 (8 MB) + Wo bf16 (2 MB)
  unsigned short* head = (unsigned short*)d_ws;
  unsigned short* wob  = head + 4194304;

  // 0) weight converts
  f32_to_bf16_k<<<1024, 256, 0, stream>>>(Wq, wqb, 1048576);
  f32_to_bf16_k<<<1024, 256, 0, stream>>>(Wk, wkb, 1048576);
  f32_to_bf16_k<<<1024, 256, 0, stream>>>(Wv, wvb, 1048576);
  f32_to_bf16_k<<<1024, 256, 0, stream>>>(Wo, wob, 1048576);

  // 1-3) projections
  gemm_proj<true, false><<<dim3(8, 64), 256, 0, stream>>>(Qin, wqb, bq, qf, nullptr);
  gemm_proj<true, true ><<<dim3(8, 64), 256, 0, stream>>>(Kin, wkb, bk, kf, kb);
  gemm_proj<true, false><<<dim3(8, 64), 256, 0, stream>>>(Vin, wvb, bv, vf, nullptr);

  // 4) v^T bf16
  transpose_v_k<<<dim3(32, 32), 256, 0, stream>>>(vf, vt);

  // 5) fused energy + softmax + PV (+ attention pass)
  fused_attn_k<<<dim3(32, 32), 256, 0, stream>>>(qf, kb, vt, energy, attn, head);

  // 6) out = head @ Wo^T + bo
  gemm_proj<false, false><<<dim3(8, 64), 256, 0, stream>>>(head, wob, bo, out, nullptr);
}

// Round 4
// 629.873 us; speedup vs baseline: 1.7463x; 1.1776x over previous
//
#include <hip/hip_runtime.h>

// ---------------------------------------------------------------------------
// SelfAttention forward (N=2, L=2048, E=1024, H=16, D=64), f32 in/out.
// Outputs concatenated: out | q | k | v | energy | attention
//
// Round-4 structure (5 launches):
//  0) cvt4: Wq/Wk/Wv (contiguous, dead energy region) + Wo (d_ws) -> bf16.
//  1) qkv_proj (grid.z=3): A f32 inline-cvt, B bf16 -> f32 q/k/v;
//     z==1 (k) dual-writes kb bf16 into dead `out` region.
//  2) transpose vf f32 -> vt bf16 [nh][d][l] into `out` region.
//  3) fused attention, BARRIER-FREE, swapped-operand QK^T:
//     s = mfma(K,Q) => lane holds S[k=rb+r][q=lr]: 4 consecutive k of one
//     q-row -> float4 nontemporal energy store DIRECT from accumulator.
//     exp lane-local, row-sum = 2 shfl. P bf16 -> per-wave 4KB swizzled LDS
//     (intra-wave, no barrier) -> PV MFMA. Pass 2 recomputes QK^T (K L2-hot)
//     and stores attention direct from registers (no LDS at all).
//     No max subtraction: |S| <~ 16 so exp(S/8) <= e^2, f32-safe.
//  4) out-projection: head bf16 @ Wo^T + bo -> out.
// ---------------------------------------------------------------------------

typedef __attribute__((ext_vector_type(8))) short     s16x8;   // 8 bf16
typedef __attribute__((ext_vector_type(4))) float     f32x4;
typedef __attribute__((ext_vector_type(8))) unsigned short u16x8;
typedef __attribute__((ext_vector_type(4))) unsigned short u16x4;

#define DEVINL __device__ __forceinline__

DEVINL unsigned short f2b(float f) {           // f32 -> bf16 (RNE)
  unsigned int u = __builtin_bit_cast(unsigned int, f);
  u = (u + 0x7FFFu + ((u >> 16) & 1u)) >> 16;
  return (unsigned short)u;
}

DEVINL s16x8 pack8(float4 a, float4 b) {
  s16x8 r;
  r[0] = (short)f2b(a.x); r[1] = (short)f2b(a.y);
  r[2] = (short)f2b(a.z); r[3] = (short)f2b(a.w);
  r[4] = (short)f2b(b.x); r[5] = (short)f2b(b.y);
  r[6] = (short)f2b(b.z); r[7] = (short)f2b(b.w);
  return r;
}

DEVINL f32x4 mfma16(s16x8 a, s16x8 b, f32x4 c) {
  return __builtin_amdgcn_mfma_f32_16x16x32_bf16(a, b, c, 0, 0, 0);
}

// ---------------------------------------------------------------------------
// 4 weight matrices f32->bf16 in one launch. grid (1024, 4).
// ---------------------------------------------------------------------------
__global__ __launch_bounds__(256) void cvt4_k(
    const float* __restrict__ s0, const float* __restrict__ s1,
    const float* __restrict__ s2, const float* __restrict__ s3,
    unsigned short* __restrict__ d0, unsigned short* __restrict__ d1,
    unsigned short* __restrict__ d2, unsigned short* __restrict__ d3) {
  int z = blockIdx.y;
  const float* s = (z == 0) ? s0 : (z == 1) ? s1 : (z == 2) ? s2 : s3;
  unsigned short* d = (z == 0) ? d0 : (z == 1) ? d1 : (z == 2) ? d2 : d3;
  int i = (blockIdx.x * 256 + threadIdx.x) * 4;
  float4 v = *(const float4*)(s + i);
  u16x4 o;
  o[0] = f2b(v.x); o[1] = f2b(v.y); o[2] = f2b(v.z); o[3] = f2b(v.w);
  *(u16x4*)(d + i) = o;
}

// ---------------------------------------------------------------------------
// Projection GEMM:  C[m][n] = sum_k A[m][k]*B[n][k] + bias[n]
// M=4096, N=1024, K=1024. B bf16. AF32: A f32 inline-cvt, else A bf16.
// QKV: grid.z in {0,1,2} selects A/bias/C (B and Cf use +z offsets);
//      Cb written only for z==1. Block: 4 waves, tile 64x128; grid (8,64[,3]).
// ---------------------------------------------------------------------------
template<bool AF32, bool QKV>
__global__ __launch_bounds__(256) void gemm_proj(
    const void* __restrict__ A0, const void* __restrict__ A1,
    const void* __restrict__ A2, const unsigned short* __restrict__ Bb,
    const float* __restrict__ b0, const float* __restrict__ b1,
    const float* __restrict__ b2, float* __restrict__ Cf,
    unsigned short* __restrict__ Cb) {
  int z = QKV ? blockIdx.z : 0;
  const void* Av = (z == 0) ? A0 : (z == 1) ? A1 : A2;
  const float* bias = (z == 0) ? b0 : (z == 1) ? b1 : b2;
  const unsigned short* B = Bb + (size_t)z * 1048576;
  float* C = Cf + (size_t)z * 4194304;
  unsigned short* Cw = (!QKV || z == 1) ? Cb : nullptr;

  int t = threadIdx.x, lane = t & 63, w = t >> 6;
  int m0 = blockIdx.y * 64 + (w >> 1) * 32;
  int n0 = blockIdx.x * 128 + (w & 1) * 64;
  int lr = lane & 15, kg = (lane >> 4) * 8;

  f32x4 acc[2][4] = {};
  const float* Af = (const float*)Av;
  const unsigned short* Ab = (const unsigned short*)Av;

  for (int k0 = 0; k0 < 1024; k0 += 32) {
    s16x8 a0, a1;
    if (AF32) {
      const float* p0 = Af + (size_t)(m0 + lr) * 1024 + k0 + kg;
      const float* p1 = p0 + 16 * 1024;
      a0 = pack8(*(const float4*)p0, *(const float4*)(p0 + 4));
      a1 = pack8(*(const float4*)p1, *(const float4*)(p1 + 4));
    } else {
      const unsigned short* p0 = Ab + (size_t)(m0 + lr) * 1024 + k0 + kg;
      a0 = *(const s16x8*)p0;
      a1 = *(const s16x8*)(p0 + 16 * 1024);
    }
    #pragma unroll
    for (int j = 0; j < 4; j++) {
      s16x8 bf = *(const s16x8*)(B + (size_t)(n0 + j * 16 + lr) * 1024 + k0 + kg);
      acc[0][j] = mfma16(a0, bf, acc[0][j]);
      acc[1][j] = mfma16(a1, bf, acc[1][j]);
    }
  }

  int rb = (lane >> 4) * 4;
  #pragma unroll
  for (int i = 0; i < 2; i++) {
    #pragma unroll
    for (int j = 0; j < 4; j++) {
      int col = n0 + j * 16 + lr;
      float bv = bias[col];
      #pragma unroll
      for (int r = 0; r < 4; r++) {
        int row = m0 + i * 16 + rb + r;
        float v = acc[i][j][r] + bv;
        size_t idx = (size_t)row * 1024 + col;
        C[idx] = v;
        if (Cw) Cw[idx] = f2b(v);
      }
    }
  }
}

// ---------------------------------------------------------------------------
// v (f32, [n][l][h*64+d]) -> vt (bf16, [n*16+h][d][l])
// ---------------------------------------------------------------------------
__global__ __launch_bounds__(256) void transpose_v_k(
    const float* __restrict__ vf, unsigned short* __restrict__ vt) {
  __shared__ unsigned short tile[64][72];
  int nh = blockIdx.y, n = nh >> 4, h = nh & 15;
  int l0 = blockIdx.x * 64;
  int t = threadIdx.x;
  int lr = t >> 2;
  int dc = (t & 3) * 16;
  const float* src = vf + ((size_t)(n * 2048 + l0 + lr)) * 1024 + h * 64 + dc;
  float4 a = *(const float4*)(src);
  float4 b = *(const float4*)(src + 4);
  float4 c = *(const float4*)(src + 8);
  float4 e = *(const float4*)(src + 12);
  float vals[16] = {a.x, a.y, a.z, a.w, b.x, b.y, b.z, b.w,
                    c.x, c.y, c.z, c.w, e.x, e.y, e.z, e.w};
  #pragma unroll
  for (int j = 0; j < 16; j++) tile[dc + j][lr] = f2b(vals[j]);
  __syncthreads();
  int dr = t >> 2;
  int lc = (t & 3) * 16;
  unsigned short* dst = vt + ((size_t)nh * 64 + dr) * 2048 + l0 + lc;
  *(u16x8*)(dst)     = *(const u16x8*)&tile[dr][lc];
  *(u16x8*)(dst + 8) = *(const u16x8*)&tile[dr][lc + 8];
}

// ---------------------------------------------------------------------------
// Fused attention, barrier-free. Grid (32,32) XCD-swizzled, 4 waves.
// Swapped QK^T: s[jk] = mfma(Kfrag, Qfrag) => lane holds
// S[k = c0+jk*16+rb+r][q = q0+w*16+lr]  (4 consecutive k of one q-row).
// ---------------------------------------------------------------------------
__global__ __launch_bounds__(256) void fused_attn_k(
    const float* __restrict__ qf, const unsigned short* __restrict__ kb,
    const unsigned short* __restrict__ vt, float* __restrict__ energy,
    float* __restrict__ attn, unsigned short* __restrict__ head) {
  __shared__ unsigned short plds[4][2048];   // per-wave 4KB, XOR-swizzled
  int bid = blockIdx.y * 32 + blockIdx.x;
  int cid = (bid & 7) * 128 + (bid >> 3);    // XCD-contiguous remap
  int nh = cid >> 5, qt = cid & 31;
  int n = nh >> 4, h = nh & 15;
  int q0 = qt * 64;
  int t = threadIdx.x, w = t >> 6, lane = t & 63;
  int lr = lane & 15, g = lane >> 4, kg = g * 8, rb = g * 4;
  int wrow = w * 16;

  // Q fragment (B-operand): lane owns q-row q0+wrow+lr
  const float* qrow = qf + ((size_t)(n * 2048 + q0 + wrow + lr)) * 1024 + h * 64;
  s16x8 bq0 = pack8(*(const float4*)(qrow + kg), *(const float4*)(qrow + kg + 4));
  s16x8 bq1 = pack8(*(const float4*)(qrow + 32 + kg),
                    *(const float4*)(qrow + 32 + kg + 4));

  const unsigned short* Kb = kb + (size_t)n * (2048 * 1024) + h * 64;
  const unsigned short* Vb = vt + (size_t)nh * (64 * 2048);
  float* erow = energy + (size_t)nh * (2048ull * 2048ull) +
                (size_t)(q0 + wrow + lr) * 2048;        // lane's own q-row
  float* arow = attn + (size_t)nh * (2048ull * 2048ull) +
                (size_t)(q0 + wrow + lr) * 2048;

  float lsum = 0.f;                 // partial sum for q = q0+wrow+lr
  f32x4 acc_o[4] = {};
  char* pw = (char*)&plds[w][0];
  int swz = (lr & 7) << 4;

  // ---- pass 1: energy (direct reg->HBM) + PV ----
  for (int c0 = 0; c0 < 2048; c0 += 128) {
    f32x4 s[8];
    #pragma unroll
    for (int jk = 0; jk < 8; jk++) {
      const unsigned short* kp = Kb + (size_t)(c0 + jk * 16 + lr) * 1024 + kg;
      s16x8 a0 = *(const s16x8*)kp;
      s16x8 a1 = *(const s16x8*)(kp + 32);
      f32x4 z = {};
      z = mfma16(a0, bq0, z);
      s[jk] = mfma16(a1, bq1, z);
    }
    #pragma unroll
    for (int jk = 0; jk < 8; jk++) {
      // energy: 4 consecutive k for this lane's q-row
      __builtin_nontemporal_store(s[jk], (f32x4*)(erow + c0 + jk * 16 + rb));
      float e0 = __expf(s[jk][0] * 0.125f);
      float e1 = __expf(s[jk][1] * 0.125f);
      float e2 = __expf(s[jk][2] * 0.125f);
      float e3 = __expf(s[jk][3] * 0.125f);
      lsum += (e0 + e1) + (e2 + e3);
      u16x4 p4;
      p4[0] = f2b(e0); p4[1] = f2b(e1); p4[2] = f2b(e2); p4[3] = f2b(e3);
      // P[q=lr][k-local = jk*16+rb .. +3]
      *(u16x4*)(pw + ((lr * 256 + (jk * 16 + rb) * 2) ^ swz)) = p4;
    }
    #pragma unroll
    for (int m = 0; m < 4; m++) {
      s16x8 pa = *(const s16x8*)(pw + ((lr * 256 + (m * 32 + kg) * 2) ^ swz));
      #pragma unroll
      for (int nf = 0; nf < 4; nf++) {
        s16x8 bv = *(const s16x8*)(Vb + (size_t)(nf * 16 + lr) * 2048 +
                                   c0 + m * 32 + kg);
        acc_o[nf] = mfma16(pa, bv, acc_o[nf]);
      }
    }
  }

  // full row sum for q=lr (reduce over the 4 lanes sharing lr)
  lsum += __shfl_xor(lsum, 16);
  lsum += __shfl_xor(lsum, 32);
  float inv = 1.0f / lsum;                       // for q = q0+wrow+lr
  float invr[4];
  #pragma unroll
  for (int r = 0; r < 4; r++) invr[r] = __shfl(inv, rb + r);

  // head = O / l  (bf16); acc_o rows are q = rb+r, cols d = nf*16+lr
  unsigned short* hrow = head + ((size_t)(n * 2048 + q0 + wrow)) * 1024 + h * 64;
  #pragma unroll
  for (int nf = 0; nf < 4; nf++)
    #pragma unroll
    for (int r = 0; r < 4; r++)
      hrow[(size_t)(rb + r) * 1024 + nf * 16 + lr] = f2b(acc_o[nf][r] * invr[r]);

  // ---- pass 2: attention = exp(s/8)*inv, direct reg->HBM ----
  for (int c0 = 0; c0 < 2048; c0 += 128) {
    #pragma unroll
    for (int jk = 0; jk < 8; jk++) {
      const unsigned short* kp = Kb + (size_t)(c0 + jk * 16 + lr) * 1024 + kg;
      s16x8 a0 = *(const s16x8*)kp;
      s16x8 a1 = *(const s16x8*)(kp + 32);
      f32x4 z = {};
      z = mfma16(a0, bq0, z);
      f32x4 sv = mfma16(a1, bq1, z);
      f32x4 a4;
      a4[0] = __expf(sv[0] * 0.125f) * inv;
      a4[1] = __expf(sv[1] * 0.125f) * inv;
      a4[2] = __expf(sv[2] * 0.125f) * inv;
      a4[3] = __expf(sv[3] * 0.125f) * inv;
      __builtin_nontemporal_store(a4, (f32x4*)(arow + c0 + jk * 16 + rb));
    }
  }
}

// ---------------------------------------------------------------------------
extern "C" void kernel_launch(void* const* d_in, const int* in_sizes, int n_in,
                              void* d_out, int out_size, void* d_ws, size_t ws_size,
                              hipStream_t stream) {
  const float* Vin = (const float*)d_in[0];
  const float* Kin = (const float*)d_in[1];
  const float* Qin = (const float*)d_in[2];
  const float* Wq  = (const float*)d_in[3];
  const float* bq  = (const float*)d_in[4];
  const float* Wk  = (const float*)d_in[5];
  const float* bk  = (const float*)d_in[6];
  const float* Wv  = (const float*)d_in[7];
  const float* bv  = (const float*)d_in[8];
  const float* Wo  = (const float*)d_in[9];
  const float* bo  = (const float*)d_in[10];

  float* out    = (float*)d_out;
  float* qf     = out + 4194304;          // (4096,1024) f32
  float* energy = out + 16777216;         // (2,16,2048,2048) f32
  float* attn   = out + 150994944;

  // dead `out` region (16 MB): vt bf16 (8 MB) + kb bf16 (8 MB)
  unsigned short* vt = (unsigned short*)out;            // [nh][64][2048]
  unsigned short* kb = (unsigned short*)out + 4194304;  // [n*l][e] bf16
  // dead energy region hosts bf16 weights (contiguous wq|wk|wv)
  unsigned short* wqkv = (unsigned short*)energy;
  // d_ws: head bf16 (8 MB) + Wo bf16 (2 MB)
  unsigned short* head = (unsigned short*)d_ws;
  unsigned short* wob  = head + 4194304;

  // 0) weight converts (one launch)
  cvt4_k<<<dim3(1024, 4), 256, 0, stream>>>(
      Wq, Wk, Wv, Wo, wqkv, wqkv + 1048576, wqkv + 2097152, wob);

  // 1) q/k/v projections (one launch, grid.z = 3)
  gemm_proj<true, true><<<dim3(8, 64, 3), 256, 0, stream>>>(
      Qin, Kin, Vin, wqkv, bq, bk, bv, qf, kb);

  // 2) v^T bf16   (vf = qf + 2*4194304)
  transpose_v_k<<<dim3(32, 32), 256, 0, stream>>>(qf + 8388608, vt);

  // 3) fused energy + softmax + PV + attention
  fused_attn_k<<<dim3(32, 32), 256, 0, stream>>>(qf, kb, vt, energy, attn, head);

  // 4) out = head @ Wo^T + bo
  gemm_proj<false, false><<<dim3(8, 64, 1), 256, 0, stream>>>(
      head, nullptr, nullptr, wob, bo, nullptr, nullptr, out, nullptr);
}

// Round 5
// 481.754 us; speedup vs baseline: 2.2832x; 1.3075x over previous
//
#include <hip/hip_runtime.h>

// ---------------------------------------------------------------------------
// SelfAttention forward (N=2, L=2048, E=1024, H=16, D=64), f32 in/out.
// Outputs concatenated: out | q | k | v | energy | attention
//
// Round-5 structure (5 launches):
//  0) cvt7: Wq/Wk/Wv/Wo + Qin/Kin/Vin -> bf16 (dead energy region / d_ws).
//  1) qkv projections (grid.z=3): m97-style LDS GEMM, bf16 in -> f32 q/k/v;
//     z==1 (k) dual-writes kb bf16 into dead `out` region.
//  2) transpose vf f32 -> vt bf16 [nh][d][l] into `out` region.
//  3) fused attention (UNCHANGED from round 4): barrier-free swapped-operand
//     QK^T, direct nontemporal energy/attention stores, per-wave swizzled
//     P-LDS, online row sums, head bf16 -> d_ws.
//  4) out-projection: m97-style GEMM, head bf16 @ Wo^T + bo -> out.
//
// m97 GEMM structure per guide §5: 128x128 tile, BK=32, 4 waves (64x64 each),
// global_load_lds width=16 staging (linear LDS, wave-uniform base + lane*16),
// 8 ds_read_b128 + 16 MFMA per K-step, 2 barriers per K-step.
// ---------------------------------------------------------------------------

typedef __attribute__((ext_vector_type(8))) short     s16x8;   // 8 bf16
typedef __attribute__((ext_vector_type(4))) float     f32x4;
typedef __attribute__((ext_vector_type(8))) unsigned short u16x8;
typedef __attribute__((ext_vector_type(4))) unsigned short u16x4;

#define DEVINL __device__ __forceinline__

DEVINL unsigned short f2b(float f) {           // f32 -> bf16 (RNE)
  unsigned int u = __builtin_bit_cast(unsigned int, f);
  u = (u + 0x7FFFu + ((u >> 16) & 1u)) >> 16;
  return (unsigned short)u;
}

DEVINL s16x8 pack8(float4 a, float4 b) {
  s16x8 r;
  r[0] = (short)f2b(a.x); r[1] = (short)f2b(a.y);
  r[2] = (short)f2b(a.z); r[3] = (short)f2b(a.w);
  r[4] = (short)f2b(b.x); r[5] = (short)f2b(b.y);
  r[6] = (short)f2b(b.z); r[7] = (short)f2b(b.w);
  return r;
}

DEVINL f32x4 mfma16(s16x8 a, s16x8 b, f32x4 c) {
  return __builtin_amdgcn_mfma_f32_16x16x32_bf16(a, b, c, 0, 0, 0);
}

DEVINL void gload16(const void* g, void* l) {  // 16B global -> LDS direct
  __builtin_amdgcn_global_load_lds(
      (const __attribute__((address_space(1))) void*)g,
      (__attribute__((address_space(3))) void*)l, 16, 0, 0);
}

// ---------------------------------------------------------------------------
// 7 f32->bf16 converts in one launch. grid (2048, 7).
// z 0-2: Wq/Wk/Wv -> dw (contiguous), z 3: Wo -> dwo, z 4-6: Q/K/V -> dx.
// ---------------------------------------------------------------------------
__global__ __launch_bounds__(256) void cvt7_k(
    const float* __restrict__ w0, const float* __restrict__ w1,
    const float* __restrict__ w2, const float* __restrict__ w3,
    const float* __restrict__ x0, const float* __restrict__ x1,
    const float* __restrict__ x2, unsigned short* __restrict__ dw,
    unsigned short* __restrict__ dwo, unsigned short* __restrict__ dx) {
  int z = blockIdx.y;
  const float* s;
  unsigned short* d;
  int n;
  if (z < 3)      { s = (z == 0) ? w0 : (z == 1) ? w1 : w2;
                    d = dw + (size_t)z * 1048576; n = 1048576; }
  else if (z == 3){ s = w3; d = dwo; n = 1048576; }
  else            { s = (z == 4) ? x0 : (z == 5) ? x1 : x2;
                    d = dx + (size_t)(z - 4) * 4194304; n = 4194304; }
  int i = (blockIdx.x * 256 + threadIdx.x) * 8;
  if (i < n) {
    float4 a = *(const float4*)(s + i);
    float4 b = *(const float4*)(s + i + 4);
    u16x8 o;
    o[0] = f2b(a.x); o[1] = f2b(a.y); o[2] = f2b(a.z); o[3] = f2b(a.w);
    o[4] = f2b(b.x); o[5] = f2b(b.y); o[6] = f2b(b.z); o[7] = f2b(b.w);
    *(u16x8*)(d + i) = o;
  }
}

// ---------------------------------------------------------------------------
// m97-style NT GEMM: C[m][n] = sum_k A[m][k]*B[n][k] + bias[n]
// M=4096, N=1024, K=1024, bf16 A/B, f32 C (+ optional bf16 dual-write).
// QKV: grid.z selects slice (A/B/bias/C offsets); z==1 dual-writes Cb.
// Block 128x128, BK=32, 4 waves (2x2 of 64x64), grid (8, 32[, 3]).
// ---------------------------------------------------------------------------
template<bool QKV>
__global__ __launch_bounds__(256) void gemm_bt(
    const unsigned short* __restrict__ Ab, const unsigned short* __restrict__ Bb,
    const float* __restrict__ b0, const float* __restrict__ b1,
    const float* __restrict__ b2, float* __restrict__ Cf,
    unsigned short* __restrict__ Cb) {
  __shared__ unsigned short lA[4096];   // [128][32] bf16, linear
  __shared__ unsigned short lB[4096];
  int z = QKV ? blockIdx.z : 0;
  const unsigned short* A = Ab + (size_t)z * 4194304;
  const unsigned short* B = Bb + (size_t)z * 1048576;
  const float* bias = (z == 0) ? b0 : (z == 1) ? b1 : b2;
  float* C = Cf + (size_t)z * 4194304;
  unsigned short* Cw = (QKV && z == 1) ? Cb : nullptr;

  int t = threadIdx.x, lane = t & 63, w = t >> 6;
  int m0 = blockIdx.y * 128, n0 = blockIdx.x * 128;
  int wm = (w >> 1) * 64, wn = (w & 1) * 64;
  int lr = lane & 15, g = lane >> 4, kg = g * 8, rb = g * 4;

  // staging: thread t covers linear LDS bytes t*16 (rows 0-63) / +4096 (64-127)
  int srow = t >> 2, scol = (t & 3) * 8;
  const unsigned short* gA = A + (size_t)(m0 + srow) * 1024 + scol;
  const unsigned short* gB = B + (size_t)(n0 + srow) * 1024 + scol;
  unsigned short* dA = lA + w * 512;          // wave-uniform LDS base (elems)
  unsigned short* dB = lB + w * 512;

  f32x4 acc[4][4] = {};

  for (int k0 = 0; k0 < 1024; k0 += 32) {
    gload16(gA,             dA);
    gload16(gA + 64 * 1024, dA + 2048);
    gload16(gB,             dB);
    gload16(gB + 64 * 1024, dB + 2048);
    gA += 32; gB += 32;
    __syncthreads();
    s16x8 af[4], bf[4];
    #pragma unroll
    for (int i = 0; i < 4; i++)
      af[i] = *(const s16x8*)&lA[(wm + i * 16 + lr) * 32 + kg];
    #pragma unroll
    for (int j = 0; j < 4; j++)
      bf[j] = *(const s16x8*)&lB[(wn + j * 16 + lr) * 32 + kg];
    #pragma unroll
    for (int i = 0; i < 4; i++)
      #pragma unroll
      for (int j = 0; j < 4; j++)
        acc[i][j] = mfma16(af[i], bf[j], acc[i][j]);
    __syncthreads();
  }

  #pragma unroll
  for (int i = 0; i < 4; i++) {
    #pragma unroll
    for (int j = 0; j < 4; j++) {
      int col = n0 + wn + j * 16 + lr;
      float bv = bias[col];
      #pragma unroll
      for (int r = 0; r < 4; r++) {
        int row = m0 + wm + i * 16 + rb + r;
        float v = acc[i][j][r] + bv;
        size_t idx = (size_t)row * 1024 + col;
        C[idx] = v;
        if (Cw) Cw[idx] = f2b(v);
      }
    }
  }
}

// ---------------------------------------------------------------------------
// v (f32, [n][l][h*64+d]) -> vt (bf16, [n*16+h][d][l])
// ---------------------------------------------------------------------------
__global__ __launch_bounds__(256) void transpose_v_k(
    const float* __restrict__ vf, unsigned short* __restrict__ vt) {
  __shared__ unsigned short tile[64][72];
  int nh = blockIdx.y, n = nh >> 4, h = nh & 15;
  int l0 = blockIdx.x * 64;
  int t = threadIdx.x;
  int lr = t >> 2;
  int dc = (t & 3) * 16;
  const float* src = vf + ((size_t)(n * 2048 + l0 + lr)) * 1024 + h * 64 + dc;
  float4 a = *(const float4*)(src);
  float4 b = *(const float4*)(src + 4);
  float4 c = *(const float4*)(src + 8);
  float4 e = *(const float4*)(src + 12);
  float vals[16] = {a.x, a.y, a.z, a.w, b.x, b.y, b.z, b.w,
                    c.x, c.y, c.z, c.w, e.x, e.y, e.z, e.w};
  #pragma unroll
  for (int j = 0; j < 16; j++) tile[dc + j][lr] = f2b(vals[j]);
  __syncthreads();
  int dr = t >> 2;
  int lc = (t & 3) * 16;
  unsigned short* dst = vt + ((size_t)nh * 64 + dr) * 2048 + l0 + lc;
  *(u16x8*)(dst)     = *(const u16x8*)&tile[dr][lc];
  *(u16x8*)(dst + 8) = *(const u16x8*)&tile[dr][lc + 8];
}

// ---------------------------------------------------------------------------
// Fused attention, barrier-free (unchanged from round 4).
// Swapped QK^T: s[jk] = mfma(Kfrag, Qfrag) => lane holds
// S[k = c0+jk*16+rb+r][q = q0+w*16+lr]  (4 consecutive k of one q-row).
// ---------------------------------------------------------------------------
__global__ __launch_bounds__(256) void fused_attn_k(
    const float* __restrict__ qf, const unsigned short* __restrict__ kb,
    const unsigned short* __restrict__ vt, float* __restrict__ energy,
    float* __restrict__ attn, unsigned short* __restrict__ head) {
  __shared__ unsigned short plds[4][2048];   // per-wave 4KB, XOR-swizzled
  int bid = blockIdx.y * 32 + blockIdx.x;
  int cid = (bid & 7) * 128 + (bid >> 3);    // XCD-contiguous remap
  int nh = cid >> 5, qt = cid & 31;
  int n = nh >> 4, h = nh & 15;
  int q0 = qt * 64;
  int t = threadIdx.x, w = t >> 6, lane = t & 63;
  int lr = lane & 15, g = lane >> 4, kg = g * 8, rb = g * 4;
  int wrow = w * 16;

  const float* qrow = qf + ((size_t)(n * 2048 + q0 + wrow + lr)) * 1024 + h * 64;
  s16x8 bq0 = pack8(*(const float4*)(qrow + kg), *(const float4*)(qrow + kg + 4));
  s16x8 bq1 = pack8(*(const float4*)(qrow + 32 + kg),
                    *(const float4*)(qrow + 32 + kg + 4));

  const unsigned short* Kb = kb + (size_t)n * (2048 * 1024) + h * 64;
  const unsigned short* Vb = vt + (size_t)nh * (64 * 2048);
  float* erow = energy + (size_t)nh * (2048ull * 2048ull) +
                (size_t)(q0 + wrow + lr) * 2048;
  float* arow = attn + (size_t)nh * (2048ull * 2048ull) +
                (size_t)(q0 + wrow + lr) * 2048;

  float lsum = 0.f;
  f32x4 acc_o[4] = {};
  char* pw = (char*)&plds[w][0];
  int swz = (lr & 7) << 4;

  // ---- pass 1: energy (direct reg->HBM) + PV ----
  for (int c0 = 0; c0 < 2048; c0 += 128) {
    f32x4 s[8];
    #pragma unroll
    for (int jk = 0; jk < 8; jk++) {
      const unsigned short* kp = Kb + (size_t)(c0 + jk * 16 + lr) * 1024 + kg;
      s16x8 a0 = *(const s16x8*)kp;
      s16x8 a1 = *(const s16x8*)(kp + 32);
      f32x4 z = {};
      z = mfma16(a0, bq0, z);
      s[jk] = mfma16(a1, bq1, z);
    }
    #pragma unroll
    for (int jk = 0; jk < 8; jk++) {
      __builtin_nontemporal_store(s[jk], (f32x4*)(erow + c0 + jk * 16 + rb));
      float e0 = __expf(s[jk][0] * 0.125f);
      float e1 = __expf(s[jk][1] * 0.125f);
      float e2 = __expf(s[jk][2] * 0.125f);
      float e3 = __expf(s[jk][3] * 0.125f);
      lsum += (e0 + e1) + (e2 + e3);
      u16x4 p4;
      p4[0] = f2b(e0); p4[1] = f2b(e1); p4[2] = f2b(e2); p4[3] = f2b(e3);
      *(u16x4*)(pw + ((lr * 256 + (jk * 16 + rb) * 2) ^ swz)) = p4;
    }
    #pragma unroll
    for (int m = 0; m < 4; m++) {
      s16x8 pa = *(const s16x8*)(pw + ((lr * 256 + (m * 32 + kg) * 2) ^ swz));
      #pragma unroll
      for (int nf = 0; nf < 4; nf++) {
        s16x8 bv = *(const s16x8*)(Vb + (size_t)(nf * 16 + lr) * 2048 +
                                   c0 + m * 32 + kg);
        acc_o[nf] = mfma16(pa, bv, acc_o[nf]);
      }
    }
  }

  lsum += __shfl_xor(lsum, 16);
  lsum += __shfl_xor(lsum, 32);
  float inv = 1.0f / lsum;
  float invr[4];
  #pragma unroll
  for (int r = 0; r < 4; r++) invr[r] = __shfl(inv, rb + r);

  unsigned short* hrow = head + ((size_t)(n * 2048 + q0 + wrow)) * 1024 + h * 64;
  #pragma unroll
  for (int nf = 0; nf < 4; nf++)
    #pragma unroll
    for (int r = 0; r < 4; r++)
      hrow[(size_t)(rb + r) * 1024 + nf * 16 + lr] = f2b(acc_o[nf][r] * invr[r]);

  // ---- pass 2: attention = exp(s/8)*inv, direct reg->HBM ----
  for (int c0 = 0; c0 < 2048; c0 += 128) {
    #pragma unroll
    for (int jk = 0; jk < 8; jk++) {
      const unsigned short* kp = Kb + (size_t)(c0 + jk * 16 + lr) * 1024 + kg;
      s16x8 a0 = *(const s16x8*)kp;
      s16x8 a1 = *(const s16x8*)(kp + 32);
      f32x4 z = {};
      z = mfma16(a0, bq0, z);
      f32x4 sv = mfma16(a1, bq1, z);
      f32x4 a4;
      a4[0] = __expf(sv[0] * 0.125f) * inv;
      a4[1] = __expf(sv[1] * 0.125f) * inv;
      a4[2] = __expf(sv[2] * 0.125f) * inv;
      a4[3] = __expf(sv[3] * 0.125f) * inv;
      __builtin_nontemporal_store(a4, (f32x4*)(arow + c0 + jk * 16 + rb));
    }
  }
}

// ---------------------------------------------------------------------------
extern "C" void kernel_launch(void* const* d_in, const int* in_sizes, int n_in,
                              void* d_out, int out_size, void* d_ws, size_t ws_size,
                              hipStream_t stream) {
  const float* Vin = (const float*)d_in[0];
  const float* Kin = (const float*)d_in[1];
  const float* Qin = (const float*)d_in[2];
  const float* Wq  = (const float*)d_in[3];
  const float* bq  = (const float*)d_in[4];
  const float* Wk  = (const float*)d_in[5];
  const float* bk  = (const float*)d_in[6];
  const float* Wv  = (const float*)d_in[7];
  const float* bv  = (const float*)d_in[8];
  const float* Wo  = (const float*)d_in[9];
  const float* bo  = (const float*)d_in[10];

  float* out    = (float*)d_out;
  float* qf     = out + 4194304;          // (4096,1024) f32; kf,vf follow
  float* energy = out + 16777216;         // (2,16,2048,2048) f32
  float* attn   = out + 150994944;

  // dead `out` region (16 MB): vt bf16 (8 MB) + kb bf16 (8 MB)
  unsigned short* vt = (unsigned short*)out;            // [nh][64][2048]
  unsigned short* kb = (unsigned short*)out + 4194304;
  // dead energy region: wq|wk|wv bf16 (6 MB) then xq|xk|xv bf16 (24 MB @ +8MB)
  unsigned short* wqkv = (unsigned short*)energy;
  unsigned short* xqkv = (unsigned short*)(energy + 2097152);
  // d_ws: head bf16 (8 MB) + Wo bf16 (2 MB)
  unsigned short* head = (unsigned short*)d_ws;
  unsigned short* wob  = head + 4194304;

  // 0) converts: weights + inputs -> bf16 (one launch)
  cvt7_k<<<dim3(2048, 7), 256, 0, stream>>>(
      Wq, Wk, Wv, Wo, Qin, Kin, Vin, wqkv, wob, xqkv);

  // 1) q/k/v projections (m97-style GEMM, grid.z = 3)
  gemm_bt<true><<<dim3(8, 32, 3), 256, 0, stream>>>(
      xqkv, wqkv, bq, bk, bv, qf, kb);

  // 2) v^T bf16   (vf = qf + 2*4194304)
  transpose_v_k<<<dim3(32, 32), 256, 0, stream>>>(qf + 8388608, vt);

  // 3) fused energy + softmax + PV + attention
  fused_attn_k<<<dim3(32, 32), 256, 0, stream>>>(qf, kb, vt, energy, attn, head);

  // 4) out = head @ Wo^T + bo (m97-style GEMM)
  gemm_bt<false><<<dim3(8, 32, 1), 256, 0, stream>>>(
      head, wob, bo, bo, bo, out, nullptr);
}

// Round 6
// 465.830 us; speedup vs baseline: 2.3612x; 1.0342x over previous
//
#include <hip/hip_runtime.h>

// ---------------------------------------------------------------------------
// SelfAttention forward (N=2, L=2048, E=1024, H=16, D=64), f32 in/out.
// Outputs concatenated: out | q | k | v | energy | attention
//
// Round-6: only fused_attn_k changed vs round 5.
//  - chunk=64, per-wave 4KB f32 LDS stage (XOR swizzle, intra-wave only,
//    ZERO barriers).
//  - energy/attention stores: coalesced 256B segments, extracted from the
//    stage into registers and issued TWO chunks later, positioned in the
//    VMEM FIFO so no load-wait ever requires a store to retire
//    (vmcnt retires in issue order: stores must be >=1 full chunk older
//    than any load being waited on).
//  - P for PV packed in registers from the stage (A-layout re-read + exp);
//    separate P-LDS buffer deleted.
// ---------------------------------------------------------------------------

typedef __attribute__((ext_vector_type(8))) short     s16x8;   // 8 bf16
typedef __attribute__((ext_vector_type(4))) float     f32x4;
typedef __attribute__((ext_vector_type(8))) unsigned short u16x8;
typedef __attribute__((ext_vector_type(4))) unsigned short u16x4;

#define DEVINL __device__ __forceinline__

DEVINL unsigned short f2b(float f) {           // f32 -> bf16 (RNE)
  unsigned int u = __builtin_bit_cast(unsigned int, f);
  u = (u + 0x7FFFu + ((u >> 16) & 1u)) >> 16;
  return (unsigned short)u;
}

DEVINL s16x8 pack8(float4 a, float4 b) {
  s16x8 r;
  r[0] = (short)f2b(a.x); r[1] = (short)f2b(a.y);
  r[2] = (short)f2b(a.z); r[3] = (short)f2b(a.w);
  r[4] = (short)f2b(b.x); r[5] = (short)f2b(b.y);
  r[6] = (short)f2b(b.z); r[7] = (short)f2b(b.w);
  return r;
}

DEVINL f32x4 mfma16(s16x8 a, s16x8 b, f32x4 c) {
  return __builtin_amdgcn_mfma_f32_16x16x32_bf16(a, b, c, 0, 0, 0);
}

DEVINL void gload16(const void* g, void* l) {  // 16B global -> LDS direct
  __builtin_amdgcn_global_load_lds(
      (const __attribute__((address_space(1))) void*)g,
      (__attribute__((address_space(3))) void*)l, 16, 0, 0);
}

// ---------------------------------------------------------------------------
// 7 f32->bf16 converts in one launch. grid (2048, 7).
// ---------------------------------------------------------------------------
__global__ __launch_bounds__(256) void cvt7_k(
    const float* __restrict__ w0, const float* __restrict__ w1,
    const float* __restrict__ w2, const float* __restrict__ w3,
    const float* __restrict__ x0, const float* __restrict__ x1,
    const float* __restrict__ x2, unsigned short* __restrict__ dw,
    unsigned short* __restrict__ dwo, unsigned short* __restrict__ dx) {
  int z = blockIdx.y;
  const float* s;
  unsigned short* d;
  int n;
  if (z < 3)      { s = (z == 0) ? w0 : (z == 1) ? w1 : w2;
                    d = dw + (size_t)z * 1048576; n = 1048576; }
  else if (z == 3){ s = w3; d = dwo; n = 1048576; }
  else            { s = (z == 4) ? x0 : (z == 5) ? x1 : x2;
                    d = dx + (size_t)(z - 4) * 4194304; n = 4194304; }
  int i = (blockIdx.x * 256 + threadIdx.x) * 8;
  if (i < n) {
    float4 a = *(const float4*)(s + i);
    float4 b = *(const float4*)(s + i + 4);
    u16x8 o;
    o[0] = f2b(a.x); o[1] = f2b(a.y); o[2] = f2b(a.z); o[3] = f2b(a.w);
    o[4] = f2b(b.x); o[5] = f2b(b.y); o[6] = f2b(b.z); o[7] = f2b(b.w);
    *(u16x8*)(d + i) = o;
  }
}

// ---------------------------------------------------------------------------
// m97-style NT GEMM (unchanged from round 5).
// ---------------------------------------------------------------------------
template<bool QKV>
__global__ __launch_bounds__(256) void gemm_bt(
    const unsigned short* __restrict__ Ab, const unsigned short* __restrict__ Bb,
    const float* __restrict__ b0, const float* __restrict__ b1,
    const float* __restrict__ b2, float* __restrict__ Cf,
    unsigned short* __restrict__ Cb) {
  __shared__ unsigned short lA[4096];   // [128][32] bf16, linear
  __shared__ unsigned short lB[4096];
  int z = QKV ? blockIdx.z : 0;
  const unsigned short* A = Ab + (size_t)z * 4194304;
  const unsigned short* B = Bb + (size_t)z * 1048576;
  const float* bias = (z == 0) ? b0 : (z == 1) ? b1 : b2;
  float* C = Cf + (size_t)z * 4194304;
  unsigned short* Cw = (QKV && z == 1) ? Cb : nullptr;

  int t = threadIdx.x, lane = t & 63, w = t >> 6;
  int m0 = blockIdx.y * 128, n0 = blockIdx.x * 128;
  int wm = (w >> 1) * 64, wn = (w & 1) * 64;
  int lr = lane & 15, g = lane >> 4, kg = g * 8, rb = g * 4;

  int srow = t >> 2, scol = (t & 3) * 8;
  const unsigned short* gA = A + (size_t)(m0 + srow) * 1024 + scol;
  const unsigned short* gB = B + (size_t)(n0 + srow) * 1024 + scol;
  unsigned short* dA = lA + w * 512;
  unsigned short* dB = lB + w * 512;

  f32x4 acc[4][4] = {};

  for (int k0 = 0; k0 < 1024; k0 += 32) {
    gload16(gA,             dA);
    gload16(gA + 64 * 1024, dA + 2048);
    gload16(gB,             dB);
    gload16(gB + 64 * 1024, dB + 2048);
    gA += 32; gB += 32;
    __syncthreads();
    s16x8 af[4], bf[4];
    #pragma unroll
    for (int i = 0; i < 4; i++)
      af[i] = *(const s16x8*)&lA[(wm + i * 16 + lr) * 32 + kg];
    #pragma unroll
    for (int j = 0; j < 4; j++)
      bf[j] = *(const s16x8*)&lB[(wn + j * 16 + lr) * 32 + kg];
    #pragma unroll
    for (int i = 0; i < 4; i++)
      #pragma unroll
      for (int j = 0; j < 4; j++)
        acc[i][j] = mfma16(af[i], bf[j], acc[i][j]);
    __syncthreads();
  }

  #pragma unroll
  for (int i = 0; i < 4; i++) {
    #pragma unroll
    for (int j = 0; j < 4; j++) {
      int col = n0 + wn + j * 16 + lr;
      float bv = bias[col];
      #pragma unroll
      for (int r = 0; r < 4; r++) {
        int row = m0 + wm + i * 16 + rb + r;
        float v = acc[i][j][r] + bv;
        size_t idx = (size_t)row * 1024 + col;
        C[idx] = v;
        if (Cw) Cw[idx] = f2b(v);
      }
    }
  }
}

// ---------------------------------------------------------------------------
// v (f32, [n][l][h*64+d]) -> vt (bf16, [n*16+h][d][l])  (unchanged)
// ---------------------------------------------------------------------------
__global__ __launch_bounds__(256) void transpose_v_k(
    const float* __restrict__ vf, unsigned short* __restrict__ vt) {
  __shared__ unsigned short tile[64][72];
  int nh = blockIdx.y, n = nh >> 4, h = nh & 15;
  int l0 = blockIdx.x * 64;
  int t = threadIdx.x;
  int lr = t >> 2;
  int dc = (t & 3) * 16;
  const float* src = vf + ((size_t)(n * 2048 + l0 + lr)) * 1024 + h * 64 + dc;
  float4 a = *(const float4*)(src);
  float4 b = *(const float4*)(src + 4);
  float4 c = *(const float4*)(src + 8);
  float4 e = *(const float4*)(src + 12);
  float vals[16] = {a.x, a.y, a.z, a.w, b.x, b.y, b.z, b.w,
                    c.x, c.y, c.z, c.w, e.x, e.y, e.z, e.w};
  #pragma unroll
  for (int j = 0; j < 16; j++) tile[dc + j][lr] = f2b(vals[j]);
  __syncthreads();
  int dr = t >> 2;
  int lc = (t & 3) * 16;
  unsigned short* dst = vt + ((size_t)nh * 64 + dr) * 2048 + l0 + lc;
  *(u16x8*)(dst)     = *(const u16x8*)&tile[dr][lc];
  *(u16x8*)(dst + 8) = *(const u16x8*)&tile[dr][lc + 8];
}

// ---------------------------------------------------------------------------
// Fused attention, barrier-free, chunk=64, staged coalesced delayed stores.
// Swapped QK^T: lane (g,lr) of wave w holds S[k=c0+jk*16+g*4+r][q=q0+w*16+lr].
// Stage layout per wave: f32 [16 q-rows][64 k-cols], byte
//   off(q,kb) = q*256 + (kb ^ ((q&7)<<4)).
// ---------------------------------------------------------------------------
__global__ __launch_bounds__(256, 3) void fused_attn_k(
    const float* __restrict__ qf, const unsigned short* __restrict__ kb,
    const unsigned short* __restrict__ vt, float* __restrict__ energy,
    float* __restrict__ attn, unsigned short* __restrict__ head) {
  __shared__ float stage[4][1024];           // 4KB per wave
  int bid = blockIdx.y * 32 + blockIdx.x;
  int cid = (bid & 7) * 128 + (bid >> 3);    // XCD-contiguous remap
  int nh = cid >> 5, qt = cid & 31;
  int n = nh >> 4, h = nh & 15;
  int q0 = qt * 64;
  int t = threadIdx.x, w = t >> 6, lane = t & 63;
  int lr = lane & 15, g = lane >> 4, kg = g * 8, rb = g * 4;
  int wrow = w * 16;

  const float* qrow = qf + ((size_t)(n * 2048 + q0 + wrow + lr)) * 1024 + h * 64;
  s16x8 bq0 = pack8(*(const float4*)(qrow + kg), *(const float4*)(qrow + kg + 4));
  s16x8 bq1 = pack8(*(const float4*)(qrow + 32 + kg),
                    *(const float4*)(qrow + 32 + kg + 4));

  const unsigned short* Kb = kb + (size_t)n * (2048 * 1024) + h * 64;
  const unsigned short* Vb = vt + (size_t)nh * (64 * 2048);
  float* eband = energy + (size_t)nh * (2048ull * 2048ull) +
                 (size_t)(q0 + wrow) * 2048;
  float* aband = attn + (size_t)nh * (2048ull * 2048ull) +
                 (size_t)(q0 + wrow) * 2048;

  char* sb = (char*)&stage[w][0];
  int swzl = (lr & 7) << 4;
  // coalesced extract/store mapping: instr p covers rows p*4+g, 256B/row
  int xr0 = g;                         // + p*4
  int xkb = lr * 16;                   // byte col within row

  float lsum = 0.f;
  f32x4 acc_o[4] = {};
  f32x4 sA0, sA1, sA2, sA3;            // chunk i-2 (stored this iter)
  f32x4 sB0, sB1, sB2, sB3;            // chunk i-1

  // ---- pass 1: energy (staged, coalesced, 2-chunk-delayed) + PV ----
  for (int c0 = 0; c0 < 2048; c0 += 64) {
    // V loads for this chunk (oldest VMEM of the iteration after K below)
    s16x8 vv0[4], vv1[4];
    #pragma unroll
    for (int nf = 0; nf < 4; nf++) {
      const unsigned short* vp = Vb + (size_t)(nf * 16 + lr) * 2048 + c0 + kg;
      vv0[nf] = *(const s16x8*)(vp);
      vv1[nf] = *(const s16x8*)(vp + 32);
    }
    // store chunk i-2 (issued before this iter's K-load consumers matter;
    // all younger loads have >=1 chunk of slack in the vmcnt FIFO)
    if (c0 >= 128) {
      float* ep = eband + (c0 - 128);
      __builtin_nontemporal_store(sA0, (f32x4*)(ep + (size_t)(xr0)      * 2048 + lr * 4));
      __builtin_nontemporal_store(sA1, (f32x4*)(ep + (size_t)(xr0 + 4)  * 2048 + lr * 4));
      __builtin_nontemporal_store(sA2, (f32x4*)(ep + (size_t)(xr0 + 8)  * 2048 + lr * 4));
      __builtin_nontemporal_store(sA3, (f32x4*)(ep + (size_t)(xr0 + 12) * 2048 + lr * 4));
    }
    // QK^T -> stage (C-layout writes, swizzled)
    #pragma unroll
    for (int jk = 0; jk < 4; jk++) {
      const unsigned short* kp = Kb + (size_t)(c0 + jk * 16 + lr) * 1024 + kg;
      s16x8 a0 = *(const s16x8*)kp;
      s16x8 a1 = *(const s16x8*)(kp + 32);
      f32x4 z = {};
      z = mfma16(a0, bq0, z);
      f32x4 s = mfma16(a1, bq1, z);
      *(f32x4*)(sb + lr * 256 + ((jk * 64 + g * 16) ^ swzl)) = s;
    }
    // exp in A-layout + pack P in regs + PV
    #pragma unroll
    for (int m = 0; m < 2; m++) {
      f32x4 x0 = *(const f32x4*)(sb + lr * 256 + ((m * 128 + g * 32) ^ swzl));
      f32x4 x1 = *(const f32x4*)(sb + lr * 256 + ((m * 128 + g * 32 + 16) ^ swzl));
      float e0 = __expf(x0[0] * 0.125f), e1 = __expf(x0[1] * 0.125f);
      float e2 = __expf(x0[2] * 0.125f), e3 = __expf(x0[3] * 0.125f);
      float e4 = __expf(x1[0] * 0.125f), e5 = __expf(x1[1] * 0.125f);
      float e6 = __expf(x1[2] * 0.125f), e7 = __expf(x1[3] * 0.125f);
      lsum += (e0 + e1 + e2 + e3) + (e4 + e5 + e6 + e7);
      s16x8 pa;
      pa[0] = (short)f2b(e0); pa[1] = (short)f2b(e1);
      pa[2] = (short)f2b(e2); pa[3] = (short)f2b(e3);
      pa[4] = (short)f2b(e4); pa[5] = (short)f2b(e5);
      pa[6] = (short)f2b(e6); pa[7] = (short)f2b(e7);
      #pragma unroll
      for (int nf = 0; nf < 4; nf++)
        acc_o[nf] = mfma16(pa, (m == 0) ? vv0[nf] : vv1[nf], acc_o[nf]);
    }
    // shift delay pipeline, extract this chunk coalesced
    sA0 = sB0; sA1 = sB1; sA2 = sB2; sA3 = sB3;
    sB0 = *(const f32x4*)(sb + (xr0)      * 256 + (xkb ^ (((xr0)      & 7) << 4)));
    sB1 = *(const f32x4*)(sb + (xr0 + 4)  * 256 + (xkb ^ (((xr0 + 4)  & 7) << 4)));
    sB2 = *(const f32x4*)(sb + (xr0 + 8)  * 256 + (xkb ^ (((xr0 + 8)  & 7) << 4)));
    sB3 = *(const f32x4*)(sb + (xr0 + 12) * 256 + (xkb ^ (((xr0 + 12) & 7) << 4)));
  }
  { // drain last two chunks
    float* ep = eband + 1920;
    __builtin_nontemporal_store(sA0, (f32x4*)(ep + (size_t)(xr0)      * 2048 + lr * 4));
    __builtin_nontemporal_store(sA1, (f32x4*)(ep + (size_t)(xr0 + 4)  * 2048 + lr * 4));
    __builtin_nontemporal_store(sA2, (f32x4*)(ep + (size_t)(xr0 + 8)  * 2048 + lr * 4));
    __builtin_nontemporal_store(sA3, (f32x4*)(ep + (size_t)(xr0 + 12) * 2048 + lr * 4));
    ep = eband + 1984;
    __builtin_nontemporal_store(sB0, (f32x4*)(ep + (size_t)(xr0)      * 2048 + lr * 4));
    __builtin_nontemporal_store(sB1, (f32x4*)(ep + (size_t)(xr0 + 4)  * 2048 + lr * 4));
    __builtin_nontemporal_store(sB2, (f32x4*)(ep + (size_t)(xr0 + 8)  * 2048 + lr * 4));
    __builtin_nontemporal_store(sB3, (f32x4*)(ep + (size_t)(xr0 + 12) * 2048 + lr * 4));
  }

  // row sum for q = q0+wrow+lr (reduce over the 4 lanes sharing lr)
  lsum += __shfl_xor(lsum, 16);
  lsum += __shfl_xor(lsum, 32);
  float inv = 1.0f / lsum;
  float invr[4];
  #pragma unroll
  for (int r = 0; r < 4; r++) invr[r] = __shfl(inv, rb + r);

  // head = O / l  (bf16); acc_o rows q = rb+r, cols d = nf*16+lr
  unsigned short* hrow = head + ((size_t)(n * 2048 + q0 + wrow)) * 1024 + h * 64;
  #pragma unroll
  for (int nf = 0; nf < 4; nf++)
    #pragma unroll
    for (int r = 0; r < 4; r++)
      hrow[(size_t)(rb + r) * 1024 + nf * 16 + lr] = f2b(acc_o[nf][r] * invr[r]);

  // ---- pass 2: attention = exp(s/8)*inv, same staged delayed stores ----
  for (int c0 = 0; c0 < 2048; c0 += 64) {
    if (c0 >= 128) {
      float* ap = aband + (c0 - 128);
      __builtin_nontemporal_store(sA0, (f32x4*)(ap + (size_t)(xr0)      * 2048 + lr * 4));
      __builtin_nontemporal_store(sA1, (f32x4*)(ap + (size_t)(xr0 + 4)  * 2048 + lr * 4));
      __builtin_nontemporal_store(sA2, (f32x4*)(ap + (size_t)(xr0 + 8)  * 2048 + lr * 4));
      __builtin_nontemporal_store(sA3, (f32x4*)(ap + (size_t)(xr0 + 12) * 2048 + lr * 4));
    }
    #pragma unroll
    for (int jk = 0; jk < 4; jk++) {
      const unsigned short* kp = Kb + (size_t)(c0 + jk * 16 + lr) * 1024 + kg;
      s16x8 a0 = *(const s16x8*)kp;
      s16x8 a1 = *(const s16x8*)(kp + 32);
      f32x4 z = {};
      z = mfma16(a0, bq0, z);
      f32x4 sv = mfma16(a1, bq1, z);
      f32x4 a4;
      a4[0] = __expf(sv[0] * 0.125f) * inv;
      a4[1] = __expf(sv[1] * 0.125f) * inv;
      a4[2] = __expf(sv[2] * 0.125f) * inv;
      a4[3] = __expf(sv[3] * 0.125f) * inv;
      *(f32x4*)(sb + lr * 256 + ((jk * 64 + g * 16) ^ swzl)) = a4;
    }
    sA0 = sB0; sA1 = sB1; sA2 = sB2; sA3 = sB3;
    sB0 = *(const f32x4*)(sb + (xr0)      * 256 + (xkb ^ (((xr0)      & 7) << 4)));
    sB1 = *(const f32x4*)(sb + (xr0 + 4)  * 256 + (xkb ^ (((xr0 + 4)  & 7) << 4)));
    sB2 = *(const f32x4*)(sb + (xr0 + 8)  * 256 + (xkb ^ (((xr0 + 8)  & 7) << 4)));
    sB3 = *(const f32x4*)(sb + (xr0 + 12) * 256 + (xkb ^ (((xr0 + 12) & 7) << 4)));
  }
  { // drain last two chunks
    float* ap = aband + 1920;
    __builtin_nontemporal_store(sA0, (f32x4*)(ap + (size_t)(xr0)      * 2048 + lr * 4));
    __builtin_nontemporal_store(sA1, (f32x4*)(ap + (size_t)(xr0 + 4)  * 2048 + lr * 4));
    __builtin_nontemporal_store(sA2, (f32x4*)(ap + (size_t)(xr0 + 8)  * 2048 + lr * 4));
    __builtin_nontemporal_store(sA3, (f32x4*)(ap + (size_t)(xr0 + 12) * 2048 + lr * 4));
    ap = aband + 1984;
    __builtin_nontemporal_store(sB0, (f32x4*)(ap + (size_t)(xr0)      * 2048 + lr * 4));
    __builtin_nontemporal_store(sB1, (f32x4*)(ap + (size_t)(xr0 + 4)  * 2048 + lr * 4));
    __builtin_nontemporal_store(sB2, (f32x4*)(ap + (size_t)(xr0 + 8)  * 2048 + lr * 4));
    __builtin_nontemporal_store(sB3, (f32x4*)(ap + (size_t)(xr0 + 12) * 2048 + lr * 4));
  }
}

// ---------------------------------------------------------------------------
extern "C" void kernel_launch(void* const* d_in, const int* in_sizes, int n_in,
                              void* d_out, int out_size, void* d_ws, size_t ws_size,
                              hipStream_t stream) {
  const float* Vin = (const float*)d_in[0];
  const float* Kin = (const float*)d_in[1];
  const float* Qin = (const float*)d_in[2];
  const float* Wq  = (const float*)d_in[3];
  const float* bq  = (const float*)d_in[4];
  const float* Wk  = (const float*)d_in[5];
  const float* bk  = (const float*)d_in[6];
  const float* Wv  = (const float*)d_in[7];
  const float* bv  = (const float*)d_in[8];
  const float* Wo  = (const float*)d_in[9];
  const float* bo  = (const float*)d_in[10];

  float* out    = (float*)d_out;
  float* qf     = out + 4194304;          // (4096,1024) f32; kf,vf follow
  float* energy = out + 16777216;         // (2,16,2048,2048) f32
  float* attn   = out + 150994944;

  unsigned short* vt = (unsigned short*)out;            // [nh][64][2048]
  unsigned short* kb = (unsigned short*)out + 4194304;
  unsigned short* wqkv = (unsigned short*)energy;
  unsigned short* xqkv = (unsigned short*)(energy + 2097152);
  unsigned short* head = (unsigned short*)d_ws;
  unsigned short* wob  = head + 4194304;

  cvt7_k<<<dim3(2048, 7), 256, 0, stream>>>(
      Wq, Wk, Wv, Wo, Qin, Kin, Vin, wqkv, wob, xqkv);

  gemm_bt<true><<<dim3(8, 32, 3), 256, 0, stream>>>(
      xqkv, wqkv, bq, bk, bv, qf, kb);

  transpose_v_k<<<dim3(32, 32), 256, 0, stream>>>(qf + 8388608, vt);

  fused_attn_k<<<dim3(32, 32), 256, 0, stream>>>(qf, kb, vt, energy, attn, head);

  gemm_bt<false><<<dim3(8, 32, 1), 256, 0, stream>>>(
      head, wob, bo, bo, bo, out, nullptr);
}